// Round 1
// baseline (134.785 us; speedup 1.0000x reference)
//
#include <hip/hip_runtime.h>
#include <math.h>

#define NB 8
#define NQ 100
#define NQH 50
#define NCP1 3
#define NC 2
#define HIN 128
#define WIN 128
#define HOUT 512
#define WOUT 512
#define QSTR (HIN * WIN)
#define QBYTES (QSTR * 4)

#if __has_builtin(__builtin_amdgcn_exp2f)
#define EXP2F(x) __builtin_amdgcn_exp2f(x)
#else
#define EXP2F(x) exp2f(x)
#endif
#if __has_builtin(__builtin_amdgcn_rcpf)
#define RCPF(x) __builtin_amdgcn_rcpf(x)
#else
#define RCPF(x) (1.0f / (x))
#endif

__device__ __forceinline__ float bperm(int byteaddr, float v) {
  return __int_as_float(__builtin_amdgcn_ds_bpermute(byteaddr, __float_as_int(v)));
}

// R13 = R12 + grouped-reciprocal sigmoid.  Counter theory: VALUBusy 76% with
// trans ops ~12cyc/wave64 -> the 16 transcendentals per wave-q (8 exp2 +
// 8 rcp) are ~60-70% of VALU time.  The 8 rcps collapse to ONE rcp of the
// 8-way product (all operands x_i = 1+e_i >= 1, product in [1,2^65): no
// under/overflow; ~7ulp error, irrelevant vs 0.125 tol), recovering each
// 1/x_i with 21 extra v_mul_f32.  Net: -7 trans (-~84cyc) + 21 mul (+42cyc)
// per wave-q.  Everything else identical to R12 (62.0us/dispatch best:
// q-split 8 waves, saddr loads, depth-5 vmcnt(8) pipeline, bperm halo,
// LDS combine).
__global__ __launch_bounds__(512, 4)
void m2f_fused(const float* __restrict__ cls,
               const float* __restrict__ masks,
               float* __restrict__ out) {
  const int k   = blockIdx.x;   // 0..127
  const int b   = blockIdx.y;   // 0..7
  const int tid = threadIdx.x;  // 0..511

  __shared__ float2 pq[NQ];           // (p_class0, p_class1) per q
  __shared__ float  part[16][256];    // qh=1 partials: [j][r*64+lane]

  // ---- inline class softmax (keep first NC of NCP1) ----
  if (tid < NQ) {
    const float* cl = cls + (b * NQ + tid) * NCP1;
    float a0 = cl[0], a1 = cl[1], a2 = cl[2];
    float mx = fmaxf(a0, fmaxf(a1, a2));
    const float L2E = 1.4426950408889634f;
    float e0 = EXP2F((a0 - mx) * L2E);
    float e1 = EXP2F((a1 - mx) * L2E);
    float e2 = EXP2F((a2 - mx) * L2E);
    float inv = RCPF(e0 + e1 + e2);
    pq[tid] = make_float2(e0 * inv, e1 * inv);
  }
  __syncthreads();

  const int wave = tid >> 6;    // 0..7
  const int r    = wave & 3;    // output row phase (y = 4k+r)
  const int qh   = wave >> 2;   // q half: 0 -> q 0..49, 1 -> q 50..99
  const int lane = tid & 63;    // col group: x = 8*lane .. 8*lane+7
  const int q0   = qh * NQH;

  // clamped input rows + vertical weights (pre-scaled by -log2e so
  // sigmoid(x) = rcp(1 + exp2(v)), v = -log2e * x)
  const int rlo = (r < 2) ? (k > 0 ? k - 1 : 0) : k;
  const int rhi = (r < 2) ? k : (k < HIN - 1 ? k + 1 : HIN - 1);
  const float NL2E = -1.4426950408889634f;
  const float wlo = ((r == 0) ? 0.375f : (r == 1) ? 0.125f
                   : (r == 2) ? 0.875f : 0.625f) * NL2E;
  const float whi = ((r == 0) ? 0.625f : (r == 1) ? 0.875f
                   : (r == 2) ? 0.125f : 0.375f) * NL2E;

  // 32-bit byte voffsets with the q-half folded in (max ~6.6MB, fits 32b);
  // saddr stays block-uniform.
  const int voffA = q0 * QBYTES + (rlo * WIN + 2 * lane) * 4;
  const int voffB = q0 * QBYTES + (rhi * WIN + 2 * lane) * 4;
  const float* const basep = masks + (size_t)b * NQ * QSTR;  // block-uniform

  const int addrL = (lane - 1) << 2;
  const int addrR = (lane + 1) << 2;
  const bool edgeL = (lane == 0);
  const bool edgeR = (lane == 63);

  float c0[8], c1[8];
#pragma unroll
  for (int j = 0; j < 8; ++j) { c0[j] = 0.f; c1[j] = 0.f; }

  // depth-5 pipeline: 2 x float2 per stage (50 = 5*10, divides evenly)
  float2 A0, B0, A1, B1, A2, B2, A3, B3, A4, B4;

  // saddr-form loads: uniform SGPR-pair base + 32-bit VGPR voffset.
#define LOADSET(S, qrel)                                                  \
  do {                                                                    \
    asm volatile("global_load_dwordx2 %0, %2, %3\n\t"                     \
                 "global_load_dwordx2 %1, %4, %3"                         \
                 : "=&v"(A##S), "=&v"(B##S)                               \
                 : "v"(voffA + (qrel) * QBYTES), "s"(basep),              \
                   "v"(voffB + (qrel) * QBYTES));                         \
  } while (0)

  // steady state: 10 loads outstanding; stage S's pair is oldest -> wait
  // until <=8 remain.  Tied to stage regs so uses can't be hoisted above.
#define WAITS(S)                                                          \
  asm volatile("s_waitcnt vmcnt(8)" : "+v"(A##S), "+v"(B##S))

  // Sigmoid via grouped reciprocal: x_i = 1+exp2(v_i) >= 1; one rcp of
  // prod(x_i), then descend the product tree with muls.  s_i = 1/x_i.
#define COMPUTE(S, qq)                                                    \
  do {                                                                    \
    const float2 pd = pq[qq];                                             \
    float t0 = fmaf(wlo, A##S.x, whi * B##S.x);   /* col 2c   */          \
    float t1 = fmaf(wlo, A##S.y, whi * B##S.y);   /* col 2c+1 */          \
    float tLr = bperm(addrL, t1);                                         \
    float tRr = bperm(addrR, t0);                                         \
    float tL = edgeL ? t0 : tLr;                                          \
    float tR = edgeR ? t1 : tRr;                                          \
    float dm = tL - t0, dd = t1 - t0, dp = tR - t1;                       \
    float v0 = fmaf(0.375f, dm, t0);                                      \
    float v1 = fmaf(0.125f, dm, t0);                                      \
    float v2 = fmaf(0.125f, dd, t0);                                      \
    float v3 = fmaf(0.375f, dd, t0);                                      \
    float v4 = fmaf(0.625f, dd, t0);                                      \
    float v5 = fmaf(0.875f, dd, t0);                                      \
    float v6 = fmaf(0.125f, dp, t1);                                      \
    float v7 = fmaf(0.375f, dp, t1);                                      \
    float x0 = 1.0f + EXP2F(v0);                                          \
    float x1 = 1.0f + EXP2F(v1);                                          \
    float x2 = 1.0f + EXP2F(v2);                                          \
    float x3 = 1.0f + EXP2F(v3);                                          \
    float x4 = 1.0f + EXP2F(v4);                                          \
    float x5 = 1.0f + EXP2F(v5);                                          \
    float x6 = 1.0f + EXP2F(v6);                                          \
    float x7 = 1.0f + EXP2F(v7);                                          \
    float p01 = x0 * x1, p23 = x2 * x3, p45 = x4 * x5, p67 = x6 * x7;     \
    float g03 = p01 * p23, g47 = p45 * p67;                               \
    float rAll = RCPF(g03 * g47);                                         \
    float r03 = rAll * g47, r47 = rAll * g03;                             \
    float r01 = r03 * p23, r23 = r03 * p01;                               \
    float r45 = r47 * p67, r67 = r47 * p45;                               \
    float s0 = r01 * x1, s1 = r01 * x0;                                   \
    float s2 = r23 * x3, s3 = r23 * x2;                                   \
    float s4 = r45 * x5, s5 = r45 * x4;                                   \
    float s6 = r67 * x7, s7 = r67 * x6;                                   \
    c0[0] = fmaf(pd.x, s0, c0[0]);  c1[0] = fmaf(pd.y, s0, c1[0]);        \
    c0[1] = fmaf(pd.x, s1, c0[1]);  c1[1] = fmaf(pd.y, s1, c1[1]);        \
    c0[2] = fmaf(pd.x, s2, c0[2]);  c1[2] = fmaf(pd.y, s2, c1[2]);        \
    c0[3] = fmaf(pd.x, s3, c0[3]);  c1[3] = fmaf(pd.y, s3, c1[3]);        \
    c0[4] = fmaf(pd.x, s4, c0[4]);  c1[4] = fmaf(pd.y, s4, c1[4]);        \
    c0[5] = fmaf(pd.x, s5, c0[5]);  c1[5] = fmaf(pd.y, s5, c1[5]);        \
    c0[6] = fmaf(pd.x, s6, c0[6]);  c1[6] = fmaf(pd.y, s6, c1[6]);        \
    c0[7] = fmaf(pd.x, s7, c0[7]);  c1[7] = fmaf(pd.y, s7, c1[7]);        \
  } while (0)

  LOADSET(0, 0); LOADSET(1, 1); LOADSET(2, 2); LOADSET(3, 3); LOADSET(4, 4);

  // main loop: qrel = 0,5,...,40 (each iteration prefetches qrel+5..qrel+9)
  for (int q = 0; q < NQH - 5; q += 5) {
    WAITS(0); COMPUTE(0, q0 + q);     LOADSET(0, q + 5);
    WAITS(1); COMPUTE(1, q0 + q + 1); LOADSET(1, q + 6);
    WAITS(2); COMPUTE(2, q0 + q + 2); LOADSET(2, q + 7);
    WAITS(3); COMPUTE(3, q0 + q + 3); LOADSET(3, q + 8);
    WAITS(4); COMPUTE(4, q0 + q + 4); LOADSET(4, q + 9);
  }

  // tail: drain all loads, then the final 5 stages (qrel 45..49)
  asm volatile("s_waitcnt vmcnt(0)"
               : "+v"(A0), "+v"(B0), "+v"(A1), "+v"(B1), "+v"(A2), "+v"(B2),
                 "+v"(A3), "+v"(B3), "+v"(A4), "+v"(B4));
  COMPUTE(0, q0 + NQH - 5);
  COMPUTE(1, q0 + NQH - 4);
  COMPUTE(2, q0 + NQH - 3);
  COMPUTE(3, q0 + NQH - 2);
  COMPUTE(4, q0 + NQH - 1);

  // ---- combine q-halves through LDS (conflict-free: stride-1 per j) ----
  const int col = r * 64 + lane;
  if (qh == 1) {
#pragma unroll
    for (int j = 0; j < 8; ++j) { part[j][col] = c0[j]; part[j + 8][col] = c1[j]; }
  }
  __syncthreads();
  if (qh == 0) {
#pragma unroll
    for (int j = 0; j < 8; ++j) { c0[j] += part[j][col]; c1[j] += part[j + 8][col]; }

    const int y  = 4 * k + r;
    const int x0 = 8 * lane;
    float* o0 = out + (((size_t)b * NC + 0) * HOUT + y) * WOUT + x0;
    float* o1 = out + (((size_t)b * NC + 1) * HOUT + y) * WOUT + x0;
    *(float4*)o0       = make_float4(c0[0], c0[1], c0[2], c0[3]);
    *(float4*)(o0 + 4) = make_float4(c0[4], c0[5], c0[6], c0[7]);
    *(float4*)o1       = make_float4(c1[0], c1[1], c1[2], c1[3]);
    *(float4*)(o1 + 4) = make_float4(c1[4], c1[5], c1[6], c1[7]);
  }
}

extern "C" void kernel_launch(void* const* d_in, const int* in_sizes, int n_in,
                              void* d_out, int out_size, void* d_ws, size_t ws_size,
                              hipStream_t stream) {
  const float* cls   = (const float*)d_in[0];   // [8,100,3] fp32
  const float* masks = (const float*)d_in[1];   // [8,100,128,128] fp32
  float* out = (float*)d_out;                   // [8,2,512,512] fp32
  dim3 grid(HIN, NB);   // 128 k-groups x 8 batches, 8 waves/block
  m2f_fused<<<grid, 512, 0, stream>>>(cls, masks, out);
}

// Round 2
// 117.958 us; speedup vs baseline: 1.1427x; 1.1427x over previous
//
#include <hip/hip_runtime.h>
#include <math.h>

#define NB 8
#define NQ 100
#define NQH 50
#define NCP1 3
#define NC 2
#define HIN 128
#define WIN 128
#define HOUT 512
#define WOUT 512
#define QSTR (HIN * WIN)
#define QBYTES (QSTR * 4)

#if __has_builtin(__builtin_amdgcn_exp2f)
#define EXP2F(x) __builtin_amdgcn_exp2f(x)
#else
#define EXP2F(x) exp2f(x)
#endif
#if __has_builtin(__builtin_amdgcn_rcpf)
#define RCPF(x) __builtin_amdgcn_rcpf(x)
#else
#define RCPF(x) (1.0f / (x))
#endif

__device__ __forceinline__ float bperm(int byteaddr, float v) {
  return __int_as_float(__builtin_amdgcn_ds_bpermute(byteaddr, __float_as_int(v)));
}

// R14 = R12 structure (revert R13's grouped rcp) + midpoint sigma-space interp.
// Post-mortem R13: +21 VALU ops cost +8us (2.3cyc/instr issue-bound) and the
// single-rcp tree serialized the chain -> trans savings never materialized.
// R12 counter accounting: VALUBusy*dur=47us; regular VALU explains 14.3us;
// residual 33us == 16 trans * ~12cyc * 400 wave-q/SIMD.  Trans (8 exp2 +
// 8 rcp per wave-q) is ~52% of kernel time.
// R14 halves it WITHOUT chain depth: evaluate sigma at only 4 logit points
// (t0, t1, mid(t0,t1), mid(tL,t0)); the right-gap mid sigma arrives from
// lane l+1 via the existing 2nd bperm (its left-gap mid).  The 8 outputs are
// linear interps of sigma over HALF-gaps (alpha' = 0.25/0.75) -> convexity
// error ~4x smaller than full-gap sigma-interp; est. absmax ~0.05 << 0.125.
// Trans/wave-q: 16 -> 8.  VALU ~44 (unchanged).  bperm count unchanged.
__global__ __launch_bounds__(512, 4)
void m2f_fused(const float* __restrict__ cls,
               const float* __restrict__ masks,
               float* __restrict__ out) {
  const int k   = blockIdx.x;   // 0..127
  const int b   = blockIdx.y;   // 0..7
  const int tid = threadIdx.x;  // 0..511

  __shared__ float2 pq[NQ];           // (p_class0, p_class1) per q
  __shared__ float  part[16][256];    // qh=1 partials: [j][r*64+lane]

  // ---- inline class softmax (keep first NC of NCP1) ----
  if (tid < NQ) {
    const float* cl = cls + (b * NQ + tid) * NCP1;
    float a0 = cl[0], a1 = cl[1], a2 = cl[2];
    float mx = fmaxf(a0, fmaxf(a1, a2));
    const float L2E = 1.4426950408889634f;
    float e0 = EXP2F((a0 - mx) * L2E);
    float e1 = EXP2F((a1 - mx) * L2E);
    float e2 = EXP2F((a2 - mx) * L2E);
    float inv = RCPF(e0 + e1 + e2);
    pq[tid] = make_float2(e0 * inv, e1 * inv);
  }
  __syncthreads();

  const int wave = tid >> 6;    // 0..7
  const int r    = wave & 3;    // output row phase (y = 4k+r)
  const int qh   = wave >> 2;   // q half: 0 -> q 0..49, 1 -> q 50..99
  const int lane = tid & 63;    // col group: x = 8*lane .. 8*lane+7
  const int q0   = qh * NQH;

  // clamped input rows + vertical weights (pre-scaled by -log2e so
  // sigmoid(x) = rcp(1 + exp2(t)), t = -log2e * x; mids stay in this domain)
  const int rlo = (r < 2) ? (k > 0 ? k - 1 : 0) : k;
  const int rhi = (r < 2) ? k : (k < HIN - 1 ? k + 1 : HIN - 1);
  const float NL2E = -1.4426950408889634f;
  const float wlo = ((r == 0) ? 0.375f : (r == 1) ? 0.125f
                   : (r == 2) ? 0.875f : 0.625f) * NL2E;
  const float whi = ((r == 0) ? 0.625f : (r == 1) ? 0.875f
                   : (r == 2) ? 0.125f : 0.375f) * NL2E;

  // 32-bit byte voffsets with the q-half folded in (max ~6.6MB, fits 32b);
  // saddr stays block-uniform.
  const int voffA = q0 * QBYTES + (rlo * WIN + 2 * lane) * 4;
  const int voffB = q0 * QBYTES + (rhi * WIN + 2 * lane) * 4;
  const float* const basep = masks + (size_t)b * NQ * QSTR;  // block-uniform

  const int addrL = (lane - 1) << 2;
  const int addrR = (lane + 1) << 2;
  const bool edgeL = (lane == 0);
  const bool edgeR = (lane == 63);

  float c0[8], c1[8];
#pragma unroll
  for (int j = 0; j < 8; ++j) { c0[j] = 0.f; c1[j] = 0.f; }

  // depth-5 pipeline: 2 x float2 per stage (50 = 5*10, divides evenly)
  float2 A0, B0, A1, B1, A2, B2, A3, B3, A4, B4;

  // saddr-form loads: uniform SGPR-pair base + 32-bit VGPR voffset.
#define LOADSET(S, qrel)                                                  \
  do {                                                                    \
    asm volatile("global_load_dwordx2 %0, %2, %3\n\t"                     \
                 "global_load_dwordx2 %1, %4, %3"                         \
                 : "=&v"(A##S), "=&v"(B##S)                               \
                 : "v"(voffA + (qrel) * QBYTES), "s"(basep),              \
                   "v"(voffB + (qrel) * QBYTES));                         \
  } while (0)

  // steady state: 10 loads outstanding; stage S's pair is oldest -> wait
  // until <=8 remain.  Tied to stage regs so uses can't be hoisted above.
#define WAITS(S)                                                          \
  asm volatile("s_waitcnt vmcnt(8)" : "+v"(A##S), "+v"(B##S))

  // sigma at 4 logit points, outputs = sigma-space interp over half-gaps.
  // Gap L = (tL,t0): px0 @0.625, px1 @0.875 of [tL->t0] -> alpha'=0.25/0.75
  //   from mL.  Gap M = (t0,t1): px2..px5.  Gap R = (t1,tR): px6 @0.125,
  //   px7 @0.375 -> interp from s1 toward sR (= neighbor's sL via bperm).
#define COMPUTE(S, qq)                                                    \
  do {                                                                    \
    const float2 pd = pq[qq];                                             \
    float t0 = fmaf(wlo, A##S.x, whi * B##S.x);   /* col 2c   */          \
    float t1 = fmaf(wlo, A##S.y, whi * B##S.y);   /* col 2c+1 */          \
    float tLr = bperm(addrL, t1);                                         \
    float tL = edgeL ? t0 : tLr;                                          \
    float m01 = 0.5f * (t0 + t1);                                         \
    float mL  = 0.5f * (tL + t0);                                         \
    float s0  = RCPF(1.0f + EXP2F(t0));                                   \
    float s1  = RCPF(1.0f + EXP2F(t1));                                   \
    float sm  = RCPF(1.0f + EXP2F(m01));                                  \
    float sL  = RCPF(1.0f + EXP2F(mL));                                   \
    float sRr = bperm(addrR, sL);                                         \
    float sR  = edgeR ? s1 : sRr;                                         \
    float dL = s0 - sL, d0 = sm - s0, d1 = s1 - sm, dR = sR - s1;         \
    float g0 = fmaf(0.25f, dL, sL);                                       \
    float g1 = fmaf(0.75f, dL, sL);                                       \
    float g2 = fmaf(0.25f, d0, s0);                                       \
    float g3 = fmaf(0.75f, d0, s0);                                       \
    float g4 = fmaf(0.25f, d1, sm);                                       \
    float g5 = fmaf(0.75f, d1, sm);                                       \
    float g6 = fmaf(0.25f, dR, s1);                                       \
    float g7 = fmaf(0.75f, dR, s1);                                       \
    c0[0] = fmaf(pd.x, g0, c0[0]);  c1[0] = fmaf(pd.y, g0, c1[0]);        \
    c0[1] = fmaf(pd.x, g1, c0[1]);  c1[1] = fmaf(pd.y, g1, c1[1]);        \
    c0[2] = fmaf(pd.x, g2, c0[2]);  c1[2] = fmaf(pd.y, g2, c1[2]);        \
    c0[3] = fmaf(pd.x, g3, c0[3]);  c1[3] = fmaf(pd.y, g3, c1[3]);        \
    c0[4] = fmaf(pd.x, g4, c0[4]);  c1[4] = fmaf(pd.y, g4, c1[4]);        \
    c0[5] = fmaf(pd.x, g5, c0[5]);  c1[5] = fmaf(pd.y, g5, c1[5]);        \
    c0[6] = fmaf(pd.x, g6, c0[6]);  c1[6] = fmaf(pd.y, g6, c1[6]);        \
    c0[7] = fmaf(pd.x, g7, c0[7]);  c1[7] = fmaf(pd.y, g7, c1[7]);        \
  } while (0)

  LOADSET(0, 0); LOADSET(1, 1); LOADSET(2, 2); LOADSET(3, 3); LOADSET(4, 4);

  // main loop: qrel = 0,5,...,40 (each iteration prefetches qrel+5..qrel+9)
  for (int q = 0; q < NQH - 5; q += 5) {
    WAITS(0); COMPUTE(0, q0 + q);     LOADSET(0, q + 5);
    WAITS(1); COMPUTE(1, q0 + q + 1); LOADSET(1, q + 6);
    WAITS(2); COMPUTE(2, q0 + q + 2); LOADSET(2, q + 7);
    WAITS(3); COMPUTE(3, q0 + q + 3); LOADSET(3, q + 8);
    WAITS(4); COMPUTE(4, q0 + q + 4); LOADSET(4, q + 9);
  }

  // tail: drain all loads, then the final 5 stages (qrel 45..49)
  asm volatile("s_waitcnt vmcnt(0)"
               : "+v"(A0), "+v"(B0), "+v"(A1), "+v"(B1), "+v"(A2), "+v"(B2),
                 "+v"(A3), "+v"(B3), "+v"(A4), "+v"(B4));
  COMPUTE(0, q0 + NQH - 5);
  COMPUTE(1, q0 + NQH - 4);
  COMPUTE(2, q0 + NQH - 3);
  COMPUTE(3, q0 + NQH - 2);
  COMPUTE(4, q0 + NQH - 1);

  // ---- combine q-halves through LDS (conflict-free: stride-1 per j) ----
  const int col = r * 64 + lane;
  if (qh == 1) {
#pragma unroll
    for (int j = 0; j < 8; ++j) { part[j][col] = c0[j]; part[j + 8][col] = c1[j]; }
  }
  __syncthreads();
  if (qh == 0) {
#pragma unroll
    for (int j = 0; j < 8; ++j) { c0[j] += part[j][col]; c1[j] += part[j + 8][col]; }

    const int y  = 4 * k + r;
    const int x0 = 8 * lane;
    float* o0 = out + (((size_t)b * NC + 0) * HOUT + y) * WOUT + x0;
    float* o1 = out + (((size_t)b * NC + 1) * HOUT + y) * WOUT + x0;
    *(float4*)o0       = make_float4(c0[0], c0[1], c0[2], c0[3]);
    *(float4*)(o0 + 4) = make_float4(c0[4], c0[5], c0[6], c0[7]);
    *(float4*)o1       = make_float4(c1[0], c1[1], c1[2], c1[3]);
    *(float4*)(o1 + 4) = make_float4(c1[4], c1[5], c1[6], c1[7]);
  }
}

extern "C" void kernel_launch(void* const* d_in, const int* in_sizes, int n_in,
                              void* d_out, int out_size, void* d_ws, size_t ws_size,
                              hipStream_t stream) {
  const float* cls   = (const float*)d_in[0];   // [8,100,3] fp32
  const float* masks = (const float*)d_in[1];   // [8,100,128,128] fp32
  float* out = (float*)d_out;                   // [8,2,512,512] fp32
  dim3 grid(HIN, NB);   // 128 k-groups x 8 batches, 8 waves/block
  m2f_fused<<<grid, 512, 0, stream>>>(cls, masks, out);
}

// Round 3
// 111.488 us; speedup vs baseline: 1.2090x; 1.0580x over previous
//
#include <hip/hip_runtime.h>
#include <math.h>

#define NB 8
#define NQ 100
#define NQH 50
#define NCP1 3
#define NC 2
#define HIN 128
#define WIN 128
#define HOUT 512
#define WOUT 512
#define QSTR (HIN * WIN)
#define QBYTES (QSTR * 4)

#if __has_builtin(__builtin_amdgcn_exp2f)
#define EXP2F(x) __builtin_amdgcn_exp2f(x)
#else
#define EXP2F(x) exp2f(x)
#endif
#if __has_builtin(__builtin_amdgcn_rcpf)
#define RCPF(x) __builtin_amdgcn_rcpf(x)
#else
#define RCPF(x) (1.0f / (x))
#endif

__device__ __forceinline__ float bperm(int byteaddr, float v) {
  return __int_as_float(__builtin_amdgcn_ds_bpermute(byteaddr, __float_as_int(v)));
}

// R15 = R14 + accumulate-then-interpolate.  R14 validated the trans model
// (48us: 31us VALU = 14.7 regular + 16 trans).  The interp tail is LINEAR
// and pd is lane-uniform per q, so reassociate:
//   Sum_q pd*g_j  ==  interp weights applied to {Sum pd*sL, ..., Sum pd*sR}
//   Sum_q pd*sR   ==  Sum_q pd*bperm(sL)  ==  bperm(Sum_q pd*sL)
// -> loop accumulates only 4 sigma values x 2 classes (8 fma, was 8+16),
//    and the 2nd bperm + its cndmask LEAVE the loop (1 per wave, was 50).
// Per wave-q: regular VALU 44 -> ~23 ops, ds 2 -> 1, trans 8 (unchanged).
// Same linear combo reassociated -> absmax behavior identical to R14.
// Accumulators 16 -> 8 regs; LDS combine halves to 8 floats/col.
// Predict 48 -> 36-40us/dispatch.
__global__ __launch_bounds__(512, 4)
void m2f_fused(const float* __restrict__ cls,
               const float* __restrict__ masks,
               float* __restrict__ out) {
  const int k   = blockIdx.x;   // 0..127
  const int b   = blockIdx.y;   // 0..7
  const int tid = threadIdx.x;  // 0..511

  __shared__ float2 pq[NQ];           // (p_class0, p_class1) per q
  __shared__ float  part[8][256];     // qh=1 partials: [acc][r*64+lane]

  // ---- inline class softmax (keep first NC of NCP1) ----
  if (tid < NQ) {
    const float* cl = cls + (b * NQ + tid) * NCP1;
    float a0 = cl[0], a1 = cl[1], a2 = cl[2];
    float mx = fmaxf(a0, fmaxf(a1, a2));
    const float L2E = 1.4426950408889634f;
    float e0 = EXP2F((a0 - mx) * L2E);
    float e1 = EXP2F((a1 - mx) * L2E);
    float e2 = EXP2F((a2 - mx) * L2E);
    float inv = RCPF(e0 + e1 + e2);
    pq[tid] = make_float2(e0 * inv, e1 * inv);
  }
  __syncthreads();

  const int wave = tid >> 6;    // 0..7
  const int r    = wave & 3;    // output row phase (y = 4k+r)
  const int qh   = wave >> 2;   // q half: 0 -> q 0..49, 1 -> q 50..99
  const int lane = tid & 63;    // col group: x = 8*lane .. 8*lane+7
  const int q0   = qh * NQH;

  // clamped input rows + vertical weights (pre-scaled by -log2e so
  // sigmoid(x) = rcp(1 + exp2(t)), t = -log2e * x; mids stay in this domain)
  const int rlo = (r < 2) ? (k > 0 ? k - 1 : 0) : k;
  const int rhi = (r < 2) ? k : (k < HIN - 1 ? k + 1 : HIN - 1);
  const float NL2E = -1.4426950408889634f;
  const float wlo = ((r == 0) ? 0.375f : (r == 1) ? 0.125f
                   : (r == 2) ? 0.875f : 0.625f) * NL2E;
  const float whi = ((r == 0) ? 0.625f : (r == 1) ? 0.875f
                   : (r == 2) ? 0.125f : 0.375f) * NL2E;

  // 32-bit byte voffsets with the q-half folded in (max ~6.6MB, fits 32b);
  // saddr stays block-uniform.
  const int voffA = q0 * QBYTES + (rlo * WIN + 2 * lane) * 4;
  const int voffB = q0 * QBYTES + (rhi * WIN + 2 * lane) * 4;
  const float* const basep = masks + (size_t)b * NQ * QSTR;  // block-uniform

  const int addrL = (lane - 1) << 2;
  const int addrR = (lane + 1) << 2;
  const bool edgeL = (lane == 0);
  const bool edgeR = (lane == 63);

  // accumulators: Sum_q pd * sigma at the 4 eval points (x=class0,y=class1)
  float2 aSL = make_float2(0.f, 0.f);
  float2 aS0 = make_float2(0.f, 0.f);
  float2 aSM = make_float2(0.f, 0.f);
  float2 aS1 = make_float2(0.f, 0.f);

  // depth-5 pipeline: 2 x float2 per stage (50 = 5*10, divides evenly)
  float2 A0, B0, A1, B1, A2, B2, A3, B3, A4, B4;

  // saddr-form loads: uniform SGPR-pair base + 32-bit VGPR voffset.
#define LOADSET(S, qrel)                                                  \
  do {                                                                    \
    asm volatile("global_load_dwordx2 %0, %2, %3\n\t"                     \
                 "global_load_dwordx2 %1, %4, %3"                         \
                 : "=&v"(A##S), "=&v"(B##S)                               \
                 : "v"(voffA + (qrel) * QBYTES), "s"(basep),              \
                   "v"(voffB + (qrel) * QBYTES));                         \
  } while (0)

  // steady state: 10 loads outstanding; stage S's pair is oldest -> wait
  // until <=8 remain.  Tied to stage regs so uses can't be hoisted above.
#define WAITS(S)                                                          \
  asm volatile("s_waitcnt vmcnt(8)" : "+v"(A##S), "+v"(B##S))

  // sigma at 4 logit points; accumulate the weighted sigmas directly.
  // Interp to the 8 output px happens ONCE at the epilogue (linearity).
#define COMPUTE(S, qq)                                                    \
  do {                                                                    \
    const float2 pd = pq[qq];                                             \
    float t0 = fmaf(wlo, A##S.x, whi * B##S.x);   /* col 2c   */          \
    float t1 = fmaf(wlo, A##S.y, whi * B##S.y);   /* col 2c+1 */          \
    float tLr = bperm(addrL, t1);                                         \
    float tL = edgeL ? t0 : tLr;                                          \
    float m01 = 0.5f * (t0 + t1);                                         \
    float mL  = 0.5f * (tL + t0);                                         \
    float s0  = RCPF(1.0f + EXP2F(t0));                                   \
    float s1  = RCPF(1.0f + EXP2F(t1));                                   \
    float sm  = RCPF(1.0f + EXP2F(m01));                                  \
    float sL  = RCPF(1.0f + EXP2F(mL));                                   \
    aSL.x = fmaf(pd.x, sL, aSL.x);  aSL.y = fmaf(pd.y, sL, aSL.y);        \
    aS0.x = fmaf(pd.x, s0, aS0.x);  aS0.y = fmaf(pd.y, s0, aS0.y);        \
    aSM.x = fmaf(pd.x, sm, aSM.x);  aSM.y = fmaf(pd.y, sm, aSM.y);        \
    aS1.x = fmaf(pd.x, s1, aS1.x);  aS1.y = fmaf(pd.y, s1, aS1.y);        \
  } while (0)

  LOADSET(0, 0); LOADSET(1, 1); LOADSET(2, 2); LOADSET(3, 3); LOADSET(4, 4);

  // main loop: qrel = 0,5,...,40 (each iteration prefetches qrel+5..qrel+9)
  for (int q = 0; q < NQH - 5; q += 5) {
    WAITS(0); COMPUTE(0, q0 + q);     LOADSET(0, q + 5);
    WAITS(1); COMPUTE(1, q0 + q + 1); LOADSET(1, q + 6);
    WAITS(2); COMPUTE(2, q0 + q + 2); LOADSET(2, q + 7);
    WAITS(3); COMPUTE(3, q0 + q + 3); LOADSET(3, q + 8);
    WAITS(4); COMPUTE(4, q0 + q + 4); LOADSET(4, q + 9);
  }

  // tail: drain all loads, then the final 5 stages (qrel 45..49)
  asm volatile("s_waitcnt vmcnt(0)"
               : "+v"(A0), "+v"(B0), "+v"(A1), "+v"(B1), "+v"(A2), "+v"(B2),
                 "+v"(A3), "+v"(B3), "+v"(A4), "+v"(B4));
  COMPUTE(0, q0 + NQH - 5);
  COMPUTE(1, q0 + NQH - 4);
  COMPUTE(2, q0 + NQH - 3);
  COMPUTE(3, q0 + NQH - 2);
  COMPUTE(4, q0 + NQH - 1);

  // ---- combine q-halves through LDS (8 floats/col, conflict-free) ----
  const int col = r * 64 + lane;
  if (qh == 1) {
    part[0][col] = aSL.x;  part[1][col] = aSL.y;
    part[2][col] = aS0.x;  part[3][col] = aS0.y;
    part[4][col] = aSM.x;  part[5][col] = aSM.y;
    part[6][col] = aS1.x;  part[7][col] = aS1.y;
  }
  __syncthreads();
  if (qh == 0) {
    aSL.x += part[0][col];  aSL.y += part[1][col];
    aS0.x += part[2][col];  aS0.y += part[3][col];
    aSM.x += part[4][col];  aSM.y += part[5][col];
    aS1.x += part[6][col];  aS1.y += part[7][col];

    // SR = neighbor's SL (bperm of the combined sum); edge lane: SR = S1
    float SRx_r = bperm(addrR, aSL.x);
    float SRy_r = bperm(addrR, aSL.y);
    float SRx = edgeR ? aS1.x : SRx_r;
    float SRy = edgeR ? aS1.y : SRy_r;

    // final half-gap interpolation (weights 0.75/0.25), once per wave
    float o0x = fmaf(0.25f, aS0.x, 0.75f * aSL.x);
    float o1x = fmaf(0.75f, aS0.x, 0.25f * aSL.x);
    float o2x = fmaf(0.25f, aSM.x, 0.75f * aS0.x);
    float o3x = fmaf(0.75f, aSM.x, 0.25f * aS0.x);
    float o4x = fmaf(0.25f, aS1.x, 0.75f * aSM.x);
    float o5x = fmaf(0.75f, aS1.x, 0.25f * aSM.x);
    float o6x = fmaf(0.25f, SRx,   0.75f * aS1.x);
    float o7x = fmaf(0.75f, SRx,   0.25f * aS1.x);
    float o0y = fmaf(0.25f, aS0.y, 0.75f * aSL.y);
    float o1y = fmaf(0.75f, aS0.y, 0.25f * aSL.y);
    float o2y = fmaf(0.25f, aSM.y, 0.75f * aS0.y);
    float o3y = fmaf(0.75f, aSM.y, 0.25f * aS0.y);
    float o4y = fmaf(0.25f, aS1.y, 0.75f * aSM.y);
    float o5y = fmaf(0.75f, aS1.y, 0.25f * aSM.y);
    float o6y = fmaf(0.25f, SRy,   0.75f * aS1.y);
    float o7y = fmaf(0.75f, SRy,   0.25f * aS1.y);

    const int y  = 4 * k + r;
    const int x0 = 8 * lane;
    float* o0 = out + (((size_t)b * NC + 0) * HOUT + y) * WOUT + x0;
    float* o1 = out + (((size_t)b * NC + 1) * HOUT + y) * WOUT + x0;
    *(float4*)o0       = make_float4(o0x, o1x, o2x, o3x);
    *(float4*)(o0 + 4) = make_float4(o4x, o5x, o6x, o7x);
    *(float4*)o1       = make_float4(o0y, o1y, o2y, o3y);
    *(float4*)(o1 + 4) = make_float4(o4y, o5y, o6y, o7y);
  }
}

extern "C" void kernel_launch(void* const* d_in, const int* in_sizes, int n_in,
                              void* d_out, int out_size, void* d_ws, size_t ws_size,
                              hipStream_t stream) {
  const float* cls   = (const float*)d_in[0];   // [8,100,3] fp32
  const float* masks = (const float*)d_in[1];   // [8,100,128,128] fp32
  float* out = (float*)d_out;                   // [8,2,512,512] fp32
  dim3 grid(HIN, NB);   // 128 k-groups x 8 batches, 8 waves/block
  m2f_fused<<<grid, 512, 0, stream>>>(cls, masks, out);
}